// Round 2
// baseline (919.829 us; speedup 1.0000x reference)
//
#include <hip/hip_runtime.h>
#include <hip/hip_fp16.h>

// VQ codebook argmin: N=32768 queries x K=8192 codes x D=256 fp32.
// Strategy: f16 hi/lo split (3 MFMA terms) => fp32-accurate dots on the
// 2.5PF matrix pipe; fused running argmin; XOR-swizzled LDS staging via
// global_load_lds(16B) to keep ds_read_b128 conflict-free.
//
// Scaling (exact powers of 2, argmin-invariant): z*=2^4, e*=2^15, so f16
// "lo" parts avoid fp16 subnormal flush. dist_scaled = 2^19*cb_sq - 2*acc.
//
// R3: revert R2's explicit pipeline (regressed: sched_barrier pinning +
// vmcnt(0) drain + spills, WRITE_SIZE 0.5->16.9MB). Back to R1's serial
// 2-barrier structure, but 32-wide k-chunks (LDS 34KB) + K-split 4
// (grid 1024) => 4 blocks/CU instead of 2. Cross-block overlap (m114)
// is what hides the stage phase; double it.

#define N_Q   32768
#define K_CB  8192
#define D_DIM 256
#define NSPLIT 4

typedef _Float16 half8 __attribute__((ext_vector_type(8)));
typedef _Float16 half4 __attribute__((ext_vector_type(4)));
typedef float    f32x4 __attribute__((ext_vector_type(4)));

__device__ __forceinline__ void gl_lds16(const _Float16* g, _Float16* l) {
  __builtin_amdgcn_global_load_lds(
      (const __attribute__((address_space(1))) unsigned int*)g,
      (__attribute__((address_space(3))) unsigned int*)l, 16, 0, 0);
}

// ---------------- prep: z -> (hi,lo) f16, scale 2^4 ----------------
__global__ void vq_prep_z(const float* __restrict__ z,
                          _Float16* __restrict__ zh, _Float16* __restrict__ zl) {
  int i = blockIdx.x * 256 + threadIdx.x;          // 2,097,152 float4 groups
  float4 v = ((const float4*)z)[i];
  float xs[4] = {v.x * 16.0f, v.y * 16.0f, v.z * 16.0f, v.w * 16.0f};
  half4 h, l;
#pragma unroll
  for (int j = 0; j < 4; ++j) {
    _Float16 hj = (_Float16)xs[j];
    h[j] = hj;
    l[j] = (_Float16)(xs[j] - (float)hj);
  }
  ((half4*)zh)[i] = h;
  ((half4*)zl)[i] = l;
}

// ------- prep: codebook -> (hi,lo) f16 scale 2^15, plus 2^19*||e||^2 -------
__global__ void vq_prep_cb(const float* __restrict__ cb,
                           _Float16* __restrict__ eh, _Float16* __restrict__ el,
                           float* __restrict__ cbs) {
  int w = threadIdx.x >> 6, lane = threadIdx.x & 63;
  int code = blockIdx.x * 4 + w;                   // wave per code
  float4 v = ((const float4*)cb)[code * 64 + lane];
  float ss = v.x * v.x + v.y * v.y + v.z * v.z + v.w * v.w; // unscaled, like ref
  float xs[4] = {v.x * 32768.0f, v.y * 32768.0f, v.z * 32768.0f, v.w * 32768.0f};
  half4 h, l;
#pragma unroll
  for (int j = 0; j < 4; ++j) {
    _Float16 hj = (_Float16)xs[j];
    h[j] = hj;
    l[j] = (_Float16)(xs[j] - (float)hj);
  }
  ((half4*)eh)[code * 64 + lane] = h;
  ((half4*)el)[code * 64 + lane] = l;
#pragma unroll
  for (int off = 1; off < 64; off <<= 1) ss += __shfl_xor(ss, off);
  if (lane == 0) cbs[code] = ss * 524288.0f;       // 2^19 scale matches dot scale
}

// ---------------- main: fused GEMM + running argmin ----------------
// Block: 256 thr = 4 waves (2x2), tile 128 queries x 128 codes per ct-iter.
// Grid: 256 query-tiles x 4 K-splits = 1024 blocks (4/CU at 34KB LDS).
// K-loop: 8 chunks of 32 k-cols per ct; serial stage->barrier->compute.
__global__ __launch_bounds__(256, 4)
void vq_main(const _Float16* __restrict__ zh, const _Float16* __restrict__ zl,
             const _Float16* __restrict__ eh, const _Float16* __restrict__ el,
             const float* __restrict__ cbs,
             unsigned long long* __restrict__ partials) {
  // 128 rows x 32 k f16 = 8KB per array; 4 arrays = 32KB (+2KB reduce).
  __shared__ __align__(16) _Float16 Ah[4096], Al[4096], Bh[4096], Bl[4096];
  __shared__ float    redD[2][128];
  __shared__ unsigned redC[2][128];

  const int tid  = threadIdx.x;
  const int lane = tid & 63;
  const int w    = tid >> 6;
  const int q    = lane & 15;
  const int quad = lane >> 4;
  const int wrow = (w >> 1) * 64;   // wave's query-row base in tile
  const int wcol = (w & 1) * 64;    // wave's code-col base in tile

  const int qt    = blockIdx.x >> 2;
  const int split = blockIdx.x & 3;
  const int q0    = qt * 128;
  const int c0    = split * 2048;

  // Staging geometry: 512 x 16B slots per array; thread owns 2 slots.
  // Physical slot p: row = p>>2, sl = p&3; holds global k-group sl^((row>>1)&3).
  // Written linearly by gl_lds (wave base + lane*16); swizzle via GLOBAL src.
  int srow[2], sgq[2], ldst[2];
#pragma unroll
  for (int c = 0; c < 2; ++c) {
    int p   = (w * 2 + c) * 64 + lane;
    srow[c] = p >> 2;
    sgq[c]  = (p & 3) ^ ((srow[c] >> 1) & 3);
    ldst[c] = (w * 2 + c) * 512;        // f16 elems (1KB chunk per wave-slot)
  }

  // Fragment LDS offsets (f16 elems): row*32 + (quad ^ ((row>>1)&3))*8.
  // (row>>1)&3 == (q>>1)&3 since wrow+mt*16 is a multiple of 16.
  const int sw = (quad ^ ((q >> 1) & 3)) << 3;
  int offA[4], offB[4];
#pragma unroll
  for (int mt = 0; mt < 4; ++mt) {
    offA[mt] = (wrow + mt * 16 + q) * 32 + sw;
    offB[mt] = (wcol + mt * 16 + q) * 32 + sw;
  }

  float    rd[16];
  unsigned rc[16];
#pragma unroll
  for (int i = 0; i < 16; ++i) { rd[i] = 3.0e38f; rc[i] = 0u; }

  for (int ct = 0; ct < 16; ++ct) {
    const int crow0 = c0 + ct * 128;
    f32x4 acc[4][4];
#pragma unroll
    for (int mt = 0; mt < 4; ++mt)
#pragma unroll
      for (int nt = 0; nt < 4; ++nt)
        acc[mt][nt] = (f32x4){0.f, 0.f, 0.f, 0.f};

    for (int kk = 0; kk < 8; ++kk) {
      const int kcol = kk * 32;
      __syncthreads();  // WAR: previous chunk's LDS reads done
#pragma unroll
      for (int c = 0; c < 2; ++c) {
        int goff = srow[c] * 256 + kcol + sgq[c] * 8;
        gl_lds16(zh + (size_t)q0 * 256 + goff,    &Ah[ldst[c]]);
        gl_lds16(zl + (size_t)q0 * 256 + goff,    &Al[ldst[c]]);
        gl_lds16(eh + (size_t)crow0 * 256 + goff, &Bh[ldst[c]]);
        gl_lds16(el + (size_t)crow0 * 256 + goff, &Bl[ldst[c]]);
      }
      __syncthreads();  // includes vmcnt(0): staged data visible

      half8 ahf[4], alf[4], bhf[4], blf[4];
#pragma unroll
      for (int i = 0; i < 4; ++i) {
        ahf[i] = *(const half8*)&Ah[offA[i]];
        alf[i] = *(const half8*)&Al[offA[i]];
        bhf[i] = *(const half8*)&Bh[offB[i]];
        blf[i] = *(const half8*)&Bl[offB[i]];
      }
#pragma unroll
      for (int mt = 0; mt < 4; ++mt)
#pragma unroll
        for (int nt = 0; nt < 4; ++nt) {
          acc[mt][nt] = __builtin_amdgcn_mfma_f32_16x16x32_f16(ahf[mt], bhf[nt], acc[mt][nt], 0, 0, 0);
          acc[mt][nt] = __builtin_amdgcn_mfma_f32_16x16x32_f16(ahf[mt], blf[nt], acc[mt][nt], 0, 0, 0);
          acc[mt][nt] = __builtin_amdgcn_mfma_f32_16x16x32_f16(alf[mt], bhf[nt], acc[mt][nt], 0, 0, 0);
        }
    }

    // Epilogue: dist = 2^19*cb_sq - 2*acc; running (min,idx) per row.
    const int cb0 = crow0 + wcol + q;
    float cbsv[4];
#pragma unroll
    for (int nt = 0; nt < 4; ++nt) cbsv[nt] = cbs[cb0 + nt * 16];
#pragma unroll
    for (int mt = 0; mt < 4; ++mt)
#pragma unroll
      for (int r = 0; r < 4; ++r) {
        float d = fmaf(-2.0f, acc[mt][0][r], cbsv[0]);
        unsigned cidx = (unsigned)cb0;
#pragma unroll
        for (int nt = 1; nt < 4; ++nt) {
          float dn = fmaf(-2.0f, acc[mt][nt][r], cbsv[nt]);
          if (dn < d) { d = dn; cidx = (unsigned)(cb0 + nt * 16); }  // strict <: first-index ties
        }
        int ri = mt * 4 + r;
        if (d < rd[ri]) { rd[ri] = d; rc[ri] = cidx; }
      }
  }

  // Cross-lane (16 codes) then cross-wave (2 col-halves) reduce.
#pragma unroll
  for (int ri = 0; ri < 16; ++ri) {
    float d = rd[ri]; unsigned cidx = rc[ri];
#pragma unroll
    for (int off = 1; off < 16; off <<= 1) {
      float od = __shfl_xor(d, off);
      unsigned oc = __shfl_xor(cidx, off);
      if (od < d || (od == d && oc < cidx)) { d = od; cidx = oc; }
    }
    if (q == 0) {
      int row = wrow + (ri >> 2) * 16 + quad * 4 + (ri & 3);
      redD[w & 1][row] = d;
      redC[w & 1][row] = cidx;
    }
  }
  __syncthreads();
  if (tid < 128) {
    float d0 = redD[0][tid]; unsigned cc0 = redC[0][tid];
    float d1 = redD[1][tid]; unsigned cc1 = redC[1][tid];
    if (d1 < d0 || (d1 == d0 && cc1 < cc0)) { d0 = d1; cc0 = cc1; }
    unsigned u = __float_as_uint(d0);
    u = (u & 0x80000000u) ? ~u : (u | 0x80000000u);  // orderable float
    partials[(size_t)split * N_Q + q0 + tid] = ((unsigned long long)u << 32) | cc0;
  }
}

// ---------------- final: combine splits, write INT32 indices ----------------
__global__ void vq_final(const unsigned long long* __restrict__ partials,
                         int* __restrict__ out) {
  int i = blockIdx.x * 256 + threadIdx.x;  // 32768
  unsigned long long m = partials[i];
#pragma unroll
  for (int s = 1; s < NSPLIT; ++s) {
    unsigned long long b = partials[(size_t)s * N_Q + i];
    if (b < m) m = b;                      // equal dist -> lower code (low 32b)
  }
  out[i] = (int)(unsigned)(m & 0xffffffffull);
}

extern "C" void kernel_launch(void* const* d_in, const int* in_sizes, int n_in,
                              void* d_out, int out_size, void* d_ws, size_t ws_size,
                              hipStream_t stream) {
  const float* z  = (const float*)d_in[0];   // [32,32,32,256] fp32
  const float* cb = (const float*)d_in[1];   // [8192,256] fp32
  char* ws = (char*)d_ws;
  // ws layout (~41.1 MB): zh 16M | zl 16M | eh 4M | el 4M | cbs 32K | partials 1M
  _Float16* zh = (_Float16*)(ws);
  _Float16* zl = (_Float16*)(ws + (size_t)16 * 1024 * 1024);
  _Float16* eh = (_Float16*)(ws + (size_t)32 * 1024 * 1024);
  _Float16* el = (_Float16*)(ws + (size_t)36 * 1024 * 1024);
  float*    cbs = (float*)(ws + (size_t)40 * 1024 * 1024);
  unsigned long long* partials =
      (unsigned long long*)(ws + (size_t)40 * 1024 * 1024 + 65536);

  hipLaunchKernelGGL(vq_prep_z,  dim3(8192), dim3(256), 0, stream, z, zh, zl);
  hipLaunchKernelGGL(vq_prep_cb, dim3(2048), dim3(256), 0, stream, cb, eh, el, cbs);
  hipLaunchKernelGGL(vq_main,    dim3(1024), dim3(256), 0, stream,
                     zh, zl, eh, el, cbs, partials);
  hipLaunchKernelGGL(vq_final,   dim3(128),  dim3(256), 0, stream,
                     partials, (int*)d_out);
}

// Round 3
// 613.254 us; speedup vs baseline: 1.4999x; 1.4999x over previous
//
#include <hip/hip_runtime.h>
#include <hip/hip_fp16.h>

// VQ codebook argmin: N=32768 queries x K=8192 codes x D=256 fp32.
// Strategy: f16 hi/lo split (3 MFMA terms) => fp32-accurate dots on the
// 2.5PF matrix pipe; fused running argmin; XOR-swizzled LDS staging via
// global_load_lds(16B) to keep ds_read_b128 conflict-free.
//
// Scaling (exact powers of 2, argmin-invariant): z*=2^4, e*=2^15, so f16
// "lo" parts avoid fp16 subnormal flush. dist_scaled = 2^19*cb_sq - 2*acc.
//
// R4: guide's verified minimal 2-phase dbuf recipe (T3 box). 32-wide
// k-chunks double-buffered (66KB LDS keeps 2 blocks/CU). Per chunk:
// STAGE(next -> buf^1), ds_read frags from buf, 48 MFMA, vmcnt(0),
// ONE s_barrier. No sched_barrier (m141 regression), no setprio, no
// second barrier, all stage addresses = base ptr + compile-time imm.
// R3's launch_bounds(256,4) spilled (VGPR 64, WRITE 632MB) - reverted.

#define N_Q   32768
#define K_CB  8192
#define D_DIM 256

typedef _Float16 half8 __attribute__((ext_vector_type(8)));
typedef _Float16 half4 __attribute__((ext_vector_type(4)));
typedef float    f32x4 __attribute__((ext_vector_type(4)));

__device__ __forceinline__ void gl_lds16(const _Float16* g, _Float16* l) {
  __builtin_amdgcn_global_load_lds(
      (const __attribute__((address_space(1))) unsigned int*)g,
      (__attribute__((address_space(3))) unsigned int*)l, 16, 0, 0);
}

// ---------------- prep: z -> (hi,lo) f16, scale 2^4 ----------------
__global__ void vq_prep_z(const float* __restrict__ z,
                          _Float16* __restrict__ zh, _Float16* __restrict__ zl) {
  int i = blockIdx.x * 256 + threadIdx.x;          // 2,097,152 float4 groups
  float4 v = ((const float4*)z)[i];
  float xs[4] = {v.x * 16.0f, v.y * 16.0f, v.z * 16.0f, v.w * 16.0f};
  half4 h, l;
#pragma unroll
  for (int j = 0; j < 4; ++j) {
    _Float16 hj = (_Float16)xs[j];
    h[j] = hj;
    l[j] = (_Float16)(xs[j] - (float)hj);
  }
  ((half4*)zh)[i] = h;
  ((half4*)zl)[i] = l;
}

// ------- prep: codebook -> (hi,lo) f16 scale 2^15, plus 2^19*||e||^2 -------
__global__ void vq_prep_cb(const float* __restrict__ cb,
                           _Float16* __restrict__ eh, _Float16* __restrict__ el,
                           float* __restrict__ cbs) {
  int w = threadIdx.x >> 6, lane = threadIdx.x & 63;
  int code = blockIdx.x * 4 + w;                   // wave per code
  float4 v = ((const float4*)cb)[code * 64 + lane];
  float ss = v.x * v.x + v.y * v.y + v.z * v.z + v.w * v.w; // unscaled, like ref
  float xs[4] = {v.x * 32768.0f, v.y * 32768.0f, v.z * 32768.0f, v.w * 32768.0f};
  half4 h, l;
#pragma unroll
  for (int j = 0; j < 4; ++j) {
    _Float16 hj = (_Float16)xs[j];
    h[j] = hj;
    l[j] = (_Float16)(xs[j] - (float)hj);
  }
  ((half4*)eh)[code * 64 + lane] = h;
  ((half4*)el)[code * 64 + lane] = l;
#pragma unroll
  for (int off = 1; off < 64; off <<= 1) ss += __shfl_xor(ss, off);
  if (lane == 0) cbs[code] = ss * 524288.0f;       // 2^19 scale matches dot scale
}

// ---------------- main: fused GEMM + running argmin ----------------
// Block: 256 thr = 4 waves (2x2), tile 128 queries x 128 codes per ct-iter.
// Grid: 256 query-tiles x 2 K-splits = 512 blocks (2/CU at 66KB LDS).
// K-loop: 8 chunks of 32 k-cols per ct, double-buffered, 1 barrier/chunk.
__global__ __launch_bounds__(256, 2)
void vq_main(const _Float16* __restrict__ zh, const _Float16* __restrict__ zl,
             const _Float16* __restrict__ eh, const _Float16* __restrict__ el,
             const float* __restrict__ cbs,
             unsigned long long* __restrict__ partials) {
  // Per buffer: 128 rows x 32 k f16 = 8KB per array; x4 arrays x2 buf = 64KB.
  __shared__ __align__(16) _Float16 Ah[2][4096], Al[2][4096];
  __shared__ __align__(16) _Float16 Bh[2][4096], Bl[2][4096];
  __shared__ float    redD[2][128];
  __shared__ unsigned redC[2][128];

  const int tid  = threadIdx.x;
  const int lane = tid & 63;
  const int w    = tid >> 6;
  const int q    = lane & 15;
  const int quad = lane >> 4;
  const int wrow = (w >> 1) * 64;   // wave's query-row base in tile
  const int wcol = (w & 1) * 64;    // wave's code-col base in tile

  const int qt    = blockIdx.x >> 1;
  const int split = blockIdx.x & 1;
  const int q0    = qt * 128;
  const int c0    = split * 4096;

  // Staging geometry: 512 x 16B slots per array-buffer; thread owns 2 slots.
  // Physical slot p: row = p>>2, sl = p&3; holds k-group sl^((row>>1)&3).
  // Written linearly by gl_lds (wave base + lane*16); swizzle via GLOBAL src.
  int p0 = (w * 2 + 0) * 64 + lane;
  int p1 = (w * 2 + 1) * 64 + lane;
  const int srow0 = p0 >> 2, srow1 = p1 >> 2;
  const int sgq0  = (p0 & 3) ^ ((srow0 >> 1) & 3);
  const int sgq1  = (p1 & 3) ^ ((srow1 >> 1) & 3);
  const int ldst0 = (w * 2 + 0) * 512;   // f16 elems (1KB chunk per wave-slot)
  const int ldst1 = (w * 2 + 1) * 512;
  const int goff0 = srow0 * 256 + sgq0 * 8;   // global f16-elem offset, row stride 256
  const int goff1 = srow1 * 256 + sgq1 * 8;

  // Per-thread global base pointers. A-side constant; B-side bumped per ct.
  const _Float16* zh0 = zh + (size_t)q0 * 256 + goff0;
  const _Float16* zh1 = zh + (size_t)q0 * 256 + goff1;
  const _Float16* zl0 = zl + (size_t)q0 * 256 + goff0;
  const _Float16* zl1 = zl + (size_t)q0 * 256 + goff1;
  const _Float16* eh0 = eh + (size_t)c0 * 256 + goff0;
  const _Float16* eh1 = eh + (size_t)c0 * 256 + goff1;
  const _Float16* el0 = el + (size_t)c0 * 256 + goff0;
  const _Float16* el1 = el + (size_t)c0 * 256 + goff1;

#define STAGE(KCOL, BUF)                              \
  { gl_lds16(zh0 + (KCOL), &Ah[BUF][ldst0]);          \
    gl_lds16(zh1 + (KCOL), &Ah[BUF][ldst1]);          \
    gl_lds16(zl0 + (KCOL), &Al[BUF][ldst0]);          \
    gl_lds16(zl1 + (KCOL), &Al[BUF][ldst1]);          \
    gl_lds16(eh0 + (KCOL), &Bh[BUF][ldst0]);          \
    gl_lds16(eh1 + (KCOL), &Bh[BUF][ldst1]);          \
    gl_lds16(el0 + (KCOL), &Bl[BUF][ldst0]);          \
    gl_lds16(el1 + (KCOL), &Bl[BUF][ldst1]); }

  // Fragment LDS offsets (f16 elems): row*32 + (quad ^ ((row>>1)&3))*8.
  // (row>>1)&3 == (q>>1)&3 since wrow+mt*16 is a multiple of 16.
  const int sw = (quad ^ ((q >> 1) & 3)) << 3;
  int offA[4], offB[4];
#pragma unroll
  for (int mt = 0; mt < 4; ++mt) {
    offA[mt] = (wrow + mt * 16 + q) * 32 + sw;
    offB[mt] = (wcol + mt * 16 + q) * 32 + sw;
  }

  float    rd[16];
  unsigned rc[16];
#pragma unroll
  for (int i = 0; i < 16; ++i) { rd[i] = 3.0e38f; rc[i] = 0u; }

  // Prologue: stage chunk 0 into buffer 0; full drain once.
  STAGE(0, 0);
  __syncthreads();

  for (int ct = 0; ct < 32; ++ct) {
    // cbs prefetch (used in epilogue; whole ct to complete)
    const int cb0 = c0 + ct * 128 + wcol + q;
    float cbsv[4];
#pragma unroll
    for (int nt = 0; nt < 4; ++nt) cbsv[nt] = cbs[cb0 + nt * 16];

    f32x4 acc[4][4];
#pragma unroll
    for (int mt = 0; mt < 4; ++mt)
#pragma unroll
      for (int nt = 0; nt < 4; ++nt)
        acc[mt][nt] = (f32x4){0.f, 0.f, 0.f, 0.f};

#pragma unroll
    for (int kk = 0; kk < 8; ++kk) {
      const int cur = kk & 1;
      // Issue next chunk's stage into the other buffer (recipe: stage FIRST).
      if (kk < 7) {
        STAGE((kk + 1) * 32, (kk + 1) & 1);
      } else {
        eh0 += 32768; eh1 += 32768; el0 += 32768; el1 += 32768;  // next ct's B panel
        if (ct < 31) STAGE(0, 0);
      }

      // Read current buffer's fragments (synced by previous chunk's
      // vmcnt(0)+barrier) and compute.
      half8 ahf[4], alf[4], bhf[4], blf[4];
#pragma unroll
      for (int i = 0; i < 4; ++i) {
        ahf[i] = *(const half8*)&Ah[cur][offA[i]];
        alf[i] = *(const half8*)&Al[cur][offA[i]];
        bhf[i] = *(const half8*)&Bh[cur][offB[i]];
        blf[i] = *(const half8*)&Bl[cur][offB[i]];
      }
#pragma unroll
      for (int mt = 0; mt < 4; ++mt)
#pragma unroll
        for (int nt = 0; nt < 4; ++nt) {
          acc[mt][nt] = __builtin_amdgcn_mfma_f32_16x16x32_f16(ahf[mt], bhf[nt], acc[mt][nt], 0, 0, 0);
          acc[mt][nt] = __builtin_amdgcn_mfma_f32_16x16x32_f16(ahf[mt], blf[nt], acc[mt][nt], 0, 0, 0);
          acc[mt][nt] = __builtin_amdgcn_mfma_f32_16x16x32_f16(alf[mt], bhf[nt], acc[mt][nt], 0, 0, 0);
        }

      // Next-chunk loads were issued before MFMA: the drain is cheap.
      asm volatile("s_waitcnt vmcnt(0)" ::: "memory");
      __builtin_amdgcn_s_barrier();
    }

    // Epilogue: dist = 2^19*cb_sq - 2*acc; running (min,idx) per row.
#pragma unroll
    for (int mt = 0; mt < 4; ++mt)
#pragma unroll
      for (int r = 0; r < 4; ++r) {
        float d = fmaf(-2.0f, acc[mt][0][r], cbsv[0]);
        unsigned cidx = (unsigned)cb0;
#pragma unroll
        for (int nt = 1; nt < 4; ++nt) {
          float dn = fmaf(-2.0f, acc[mt][nt][r], cbsv[nt]);
          if (dn < d) { d = dn; cidx = (unsigned)(cb0 + nt * 16); }  // strict <: first-index ties
        }
        int ri = mt * 4 + r;
        if (d < rd[ri]) { rd[ri] = d; rc[ri] = cidx; }
      }
  }

  // Cross-lane (16 codes) then cross-wave (2 col-halves) reduce.
#pragma unroll
  for (int ri = 0; ri < 16; ++ri) {
    float d = rd[ri]; unsigned cidx = rc[ri];
#pragma unroll
    for (int off = 1; off < 16; off <<= 1) {
      float od = __shfl_xor(d, off);
      unsigned oc = __shfl_xor(cidx, off);
      if (od < d || (od == d && oc < cidx)) { d = od; cidx = oc; }
    }
    if (q == 0) {
      int row = wrow + (ri >> 2) * 16 + quad * 4 + (ri & 3);
      redD[w & 1][row] = d;
      redC[w & 1][row] = cidx;
    }
  }
  __syncthreads();
  if (tid < 128) {
    float d0 = redD[0][tid]; unsigned cc0 = redC[0][tid];
    float d1 = redD[1][tid]; unsigned cc1 = redC[1][tid];
    if (d1 < d0 || (d1 == d0 && cc1 < cc0)) { d0 = d1; cc0 = cc1; }
    unsigned u = __float_as_uint(d0);
    u = (u & 0x80000000u) ? ~u : (u | 0x80000000u);  // orderable float
    partials[(size_t)split * N_Q + q0 + tid] = ((unsigned long long)u << 32) | cc0;
  }
#undef STAGE
}

// ---------------- final: combine splits, write INT32 indices ----------------
__global__ void vq_final(const unsigned long long* __restrict__ partials,
                         int* __restrict__ out) {
  int i = blockIdx.x * 256 + threadIdx.x;  // 32768
  unsigned long long a = partials[i], b = partials[(size_t)N_Q + i];
  unsigned long long m = (b < a) ? b : a;  // equal dist -> lower code (low 32b)
  out[i] = (int)(unsigned)(m & 0xffffffffull);
}

extern "C" void kernel_launch(void* const* d_in, const int* in_sizes, int n_in,
                              void* d_out, int out_size, void* d_ws, size_t ws_size,
                              hipStream_t stream) {
  const float* z  = (const float*)d_in[0];   // [32,32,32,256] fp32
  const float* cb = (const float*)d_in[1];   // [8192,256] fp32
  char* ws = (char*)d_ws;
  // ws layout (~40.6 MB): zh 16M | zl 16M | eh 4M | el 4M | cbs 32K | partials 512K
  _Float16* zh = (_Float16*)(ws);
  _Float16* zl = (_Float16*)(ws + (size_t)16 * 1024 * 1024);
  _Float16* eh = (_Float16*)(ws + (size_t)32 * 1024 * 1024);
  _Float16* el = (_Float16*)(ws + (size_t)36 * 1024 * 1024);
  float*    cbs = (float*)(ws + (size_t)40 * 1024 * 1024);
  unsigned long long* partials =
      (unsigned long long*)(ws + (size_t)40 * 1024 * 1024 + 65536);

  hipLaunchKernelGGL(vq_prep_z,  dim3(8192), dim3(256), 0, stream, z, zh, zl);
  hipLaunchKernelGGL(vq_prep_cb, dim3(2048), dim3(256), 0, stream, cb, eh, el, cbs);
  hipLaunchKernelGGL(vq_main,    dim3(512),  dim3(256), 0, stream,
                     zh, zl, eh, el, cbs, partials);
  hipLaunchKernelGGL(vq_final,   dim3(128),  dim3(256), 0, stream,
                     partials, (int*)d_out);
}

// Round 5
// 437.178 us; speedup vs baseline: 2.1040x; 1.4028x over previous
//
#include <hip/hip_runtime.h>
#include <hip/hip_fp16.h>

// VQ codebook argmin: N=32768 queries x K=8192 codes x D=256 fp32.
// Strategy: f16 hi/lo split (3 MFMA terms) => fp32-accurate dots on the
// 2.5PF matrix pipe; fused running argmin; XOR-swizzled LDS staging via
// global_load_lds(16B), conflict-free ds_read_b128.
//
// Scaling (exact powers of 2, argmin-invariant): z*=2^4, e*=2^15, so f16
// "lo" parts avoid fp16 subnormal flush. dist_scaled = 2^19*cb_sq - 2*acc.
//
// R6: A-RESIDENT, FULL D PER BLOCK. R5's bug: it split D=256 across
// blocks and min-combined partial distances (must be summed) -> wrong.
// Now each block owns a 128-query tile with its FULL 256-k A panel
// resident in LDS (128KB), and streams all 8192 codes in 32-k chunks
// (B dbuf 32KB). LDS = 160KB exactly -> 1 block/CU (proven regime:
// HK/AITER attn use 160KB blocks). Overlap comes from the B double
// buffer: stage next chunk -> 48 MFMA -> vmcnt(0) -> s_barrier.
// Staged traffic 4.19GB -> 2.18GB (the R1 49%-MfmaUtil cap was staging
// BW ~11 TB/s vs ~20 needed). No split -> vq_final removed, main writes
// int32 directly.

#define N_Q   32768
#define K_CB  8192
#define D_DIM 256

typedef _Float16 half8 __attribute__((ext_vector_type(8)));
typedef _Float16 half4 __attribute__((ext_vector_type(4)));
typedef float    f32x4 __attribute__((ext_vector_type(4)));

__device__ __forceinline__ void gl_lds16(const _Float16* g, _Float16* l) {
  __builtin_amdgcn_global_load_lds(
      (const __attribute__((address_space(1))) unsigned int*)g,
      (__attribute__((address_space(3))) unsigned int*)l, 16, 0, 0);
}

// ---------------- prep: z -> (hi,lo) f16, scale 2^4 ----------------
__global__ void vq_prep_z(const float* __restrict__ z,
                          _Float16* __restrict__ zh, _Float16* __restrict__ zl) {
  int i = blockIdx.x * 256 + threadIdx.x;          // 2,097,152 float4 groups
  float4 v = ((const float4*)z)[i];
  float xs[4] = {v.x * 16.0f, v.y * 16.0f, v.z * 16.0f, v.w * 16.0f};
  half4 h, l;
#pragma unroll
  for (int j = 0; j < 4; ++j) {
    _Float16 hj = (_Float16)xs[j];
    h[j] = hj;
    l[j] = (_Float16)(xs[j] - (float)hj);
  }
  ((half4*)zh)[i] = h;
  ((half4*)zl)[i] = l;
}

// ------- prep: codebook -> (hi,lo) f16 scale 2^15, plus 2^19*||e||^2 -------
__global__ void vq_prep_cb(const float* __restrict__ cb,
                           _Float16* __restrict__ eh, _Float16* __restrict__ el,
                           float* __restrict__ cbs) {
  int w = threadIdx.x >> 6, lane = threadIdx.x & 63;
  int code = blockIdx.x * 4 + w;                   // wave per code
  float4 v = ((const float4*)cb)[code * 64 + lane];
  float ss = v.x * v.x + v.y * v.y + v.z * v.z + v.w * v.w; // unscaled, like ref
  float xs[4] = {v.x * 32768.0f, v.y * 32768.0f, v.z * 32768.0f, v.w * 32768.0f};
  half4 h, l;
#pragma unroll
  for (int j = 0; j < 4; ++j) {
    _Float16 hj = (_Float16)xs[j];
    h[j] = hj;
    l[j] = (_Float16)(xs[j] - (float)hj);
  }
  ((half4*)eh)[code * 64 + lane] = h;
  ((half4*)el)[code * 64 + lane] = l;
#pragma unroll
  for (int off = 1; off < 64; off <<= 1) ss += __shfl_xor(ss, off);
  if (lane == 0) cbs[code] = ss * 524288.0f;       // 2^19 scale matches dot scale
}

// ---------------- main: fused GEMM + running argmin ----------------
// Block: 256 thr = 4 waves (2x2). Tile: 128 queries (A resident, full
// D=256) x 128 codes per ct-iter, 64 ct-iters covering all 8192 codes.
// Grid: 256 blocks = 1/CU at 160KB LDS.
__global__ __launch_bounds__(256, 1)
void vq_main(const _Float16* __restrict__ zh, const _Float16* __restrict__ zl,
             const _Float16* __restrict__ eh, const _Float16* __restrict__ el,
             const float* __restrict__ cbs,
             int* __restrict__ out) {
  // Carved LDS: Ah 64K | Al 64K | Bh0 8K | Bl0 8K | Bh1 8K | Bl1 8K = 160KB.
  // redD/redC (2KB) overlay the A region after the main loop (A dead).
  __shared__ __align__(16) char smem[163840];
  _Float16* const Ah  = (_Float16*)smem;              // [128 rows][32 slots]
  _Float16* const Al  = (_Float16*)(smem + 65536);
  _Float16* const Bh0 = (_Float16*)(smem + 131072);   // [128 rows][4 slots]
  _Float16* const Bl0 = (_Float16*)(smem + 139264);
  _Float16* const Bh1 = (_Float16*)(smem + 147456);
  _Float16* const Bl1 = (_Float16*)(smem + 155648);

  const int tid  = threadIdx.x;
  const int lane = tid & 63;
  const int w    = tid >> 6;
  const int q    = lane & 15;
  const int quad = lane >> 4;
  const int wrow = (w >> 1) * 64;   // wave's query-row base in tile
  const int wcol = (w & 1) * 64;    // wave's code-col base in tile
  const int q0   = blockIdx.x * 128;

  // ---- A prologue stage (once): waves 0,1 -> Ah ; waves 2,3 -> Al ----
  // A layout: row stride 256 f16 (32 x 16B slots); phys slot s holds
  // logical k-slot s ^ (row&7). Uniform 8 lanes/bank-group on reads
  // (same distribution as a linear b128 read = conflict-free).
  // gl_lds writes linearly; swizzle applied on the GLOBAL source address.
  {
    const _Float16* asrc = (w < 2) ? zh : zl;
    _Float16* const adst = (w < 2) ? Ah : Al;
    const int wl = w & 1;
#pragma unroll
    for (int c = 0; c < 32; ++c) {
      const int ch  = wl * 32 + c;         // 64-slot chunk id, 0..63
      const int p   = ch * 64 + lane;      // slot 0..4095
      const int row = p >> 5;
      const int ksl = (p & 31) ^ (row & 7);
      gl_lds16(asrc + (size_t)(q0 + row) * 256 + ksl * 8,
               adst + ch * 512);           // wave-uniform LDS base
    }
  }

  // ---- B per-chunk staging geometry: waves 0,1 -> Bh ; 2,3 -> Bl ----
  // B layout: row stride 32 f16 (4 slots); phys slot s holds s^((row>>1)&3)
  // (R1's proven swizzle, measured 0 conflicts).
  const _Float16* bptr = (w < 2) ? eh : el;   // bumped 128 code-rows per ct
  int boff[4], bldst[4];
  {
    const int wl = w & 1;
#pragma unroll
    for (int c = 0; c < 4; ++c) {
      const int ch   = wl * 4 + c;         // 0..7
      const int p    = ch * 64 + lane;     // slot 0..511
      const int brow = p >> 2;
      boff[c]  = brow * 256 + ((p & 3) ^ ((brow >> 1) & 3)) * 8;
      bldst[c] = ch * 512;
    }
  }

  // Fragment offsets. A: row*256 + ((kk*4+quad)^(q&7))*8 (kk compile-time).
  // B: row*32 + (quad^((q>>1)&3))*8 (buffer holds current chunk).
  const int xorA = q & 7;
  const int sw   = (quad ^ ((q >> 1) & 3)) << 3;
  int rowA[4], offB[4];
#pragma unroll
  for (int mt = 0; mt < 4; ++mt) {
    rowA[mt] = (wrow + mt * 16 + q) * 256;
    offB[mt] = (wcol + mt * 16 + q) * 32 + sw;
  }

  float    rd[16];
  unsigned rc[16];
#pragma unroll
  for (int i = 0; i < 16; ++i) { rd[i] = 3.0e38f; rc[i] = 0u; }

  // Stage B chunk 0 (ct=0, kk=0) into buf0; one full drain.
#pragma unroll
  for (int c = 0; c < 4; ++c)
    gl_lds16(bptr + boff[c], ((w < 2) ? Bh0 : Bl0) + bldst[c]);
  __syncthreads();   // drains A prologue + first B stage (vmcnt(0) in barrier)

  for (int ct = 0; ct < 64; ++ct) {
    const int cb0 = ct * 128 + wcol + q;
    float cbsv[4];
#pragma unroll
    for (int nt = 0; nt < 4; ++nt) cbsv[nt] = cbs[cb0 + nt * 16];

    f32x4 acc[4][4];
#pragma unroll
    for (int mt = 0; mt < 4; ++mt)
#pragma unroll
      for (int nt = 0; nt < 4; ++nt)
        acc[mt][nt] = (f32x4){0.f, 0.f, 0.f, 0.f};

#pragma unroll
    for (int kk = 0; kk < 8; ++kk) {
      _Float16* const bhc = (kk & 1) ? Bh1 : Bh0;  // current chunk
      _Float16* const blc = (kk & 1) ? Bl1 : Bl0;
      _Float16* const bdn = (w < 2) ? ((kk & 1) ? Bh0 : Bh1)   // next-chunk dest
                                    : ((kk & 1) ? Bl0 : Bl1);
      // Issue next chunk's stage into the other buffer (before compute).
      if (kk < 7) {
#pragma unroll
        for (int c = 0; c < 4; ++c)
          gl_lds16(bptr + boff[c] + (kk + 1) * 32, bdn + bldst[c]);
      } else {
        bptr += 32768;                     // next ct's 128 code-rows
        if (ct < 63) {
#pragma unroll
          for (int c = 0; c < 4; ++c)
            gl_lds16(bptr + boff[c], bdn + bldst[c]);
        }
      }

      // Read fragments (current buffer synced by previous chunk's barrier).
      half8 ahf[4], alf[4], bhf[4], blf[4];
#pragma unroll
      for (int i = 0; i < 4; ++i) {
        const int oa = rowA[i] + (((kk * 4 + quad) ^ xorA) << 3);
        ahf[i] = *(const half8*)&Ah[oa];
        alf[i] = *(const half8*)&Al[oa];
        bhf[i] = *(const half8*)&bhc[offB[i]];
        blf[i] = *(const half8*)&blc[offB[i]];
      }
#pragma unroll
      for (int mt = 0; mt < 4; ++mt)
#pragma unroll
        for (int nt = 0; nt < 4; ++nt) {
          acc[mt][nt] = __builtin_amdgcn_mfma_f32_16x16x32_f16(ahf[mt], bhf[nt], acc[mt][nt], 0, 0, 0);
          acc[mt][nt] = __builtin_amdgcn_mfma_f32_16x16x32_f16(ahf[mt], blf[nt], acc[mt][nt], 0, 0, 0);
          acc[mt][nt] = __builtin_amdgcn_mfma_f32_16x16x32_f16(alf[mt], bhf[nt], acc[mt][nt], 0, 0, 0);
        }

      // Next-chunk loads had the whole MFMA phase to land: drain is cheap.
      asm volatile("s_waitcnt vmcnt(0)" ::: "memory");
      __builtin_amdgcn_s_barrier();
    }

    // Epilogue: dist = 2^19*cb_sq - 2*acc; running (min,idx) per row.
    // Runs while next ct's chunk-0 stage (issued at kk=7) is in flight.
#pragma unroll
    for (int mt = 0; mt < 4; ++mt)
#pragma unroll
      for (int r = 0; r < 4; ++r) {
        float d = fmaf(-2.0f, acc[mt][0][r], cbsv[0]);
        unsigned cidx = (unsigned)cb0;
#pragma unroll
        for (int nt = 1; nt < 4; ++nt) {
          float dn = fmaf(-2.0f, acc[mt][nt][r], cbsv[nt]);
          if (dn < d) { d = dn; cidx = (unsigned)(cb0 + nt * 16); }  // strict <: first-index ties
        }
        int ri = mt * 4 + r;
        if (d < rd[ri]) { rd[ri] = d; rc[ri] = cidx; }
      }
  }

  // Reduce arrays overlay the (now dead) A region.
  __syncthreads();                         // all LDS reads of A/B complete
  float*    const redD = (float*)smem;     // [2][128]
  unsigned* const redC = (unsigned*)(smem + 1024);

  // Cross-lane (16 codes) then cross-wave (2 col-halves) reduce.
#pragma unroll
  for (int ri = 0; ri < 16; ++ri) {
    float d = rd[ri]; unsigned cidx = rc[ri];
#pragma unroll
    for (int off = 1; off < 16; off <<= 1) {
      float od = __shfl_xor(d, off);
      unsigned oc = __shfl_xor(cidx, off);
      if (od < d || (od == d && oc < cidx)) { d = od; cidx = oc; }
    }
    if (q == 0) {
      int row = wrow + (ri >> 2) * 16 + quad * 4 + (ri & 3);
      redD[(w & 1) * 128 + row] = d;
      redC[(w & 1) * 128 + row] = cidx;
    }
  }
  __syncthreads();
  if (tid < 128) {
    float d0 = redD[tid];       unsigned cc0 = redC[tid];
    float d1 = redD[128 + tid]; unsigned cc1 = redC[128 + tid];
    if (d1 < d0 || (d1 == d0 && cc1 < cc0)) { d0 = d1; cc0 = cc1; }
    out[q0 + tid] = (int)cc0;              // int32 indices (harness dtype)
  }
}

extern "C" void kernel_launch(void* const* d_in, const int* in_sizes, int n_in,
                              void* d_out, int out_size, void* d_ws, size_t ws_size,
                              hipStream_t stream) {
  const float* z  = (const float*)d_in[0];   // [32,32,32,256] fp32
  const float* cb = (const float*)d_in[1];   // [8192,256] fp32
  char* ws = (char*)d_ws;
  // ws layout (~40 MB): zh 16M | zl 16M | eh 4M | el 4M | cbs 32K
  _Float16* zh = (_Float16*)(ws);
  _Float16* zl = (_Float16*)(ws + (size_t)16 * 1024 * 1024);
  _Float16* eh = (_Float16*)(ws + (size_t)32 * 1024 * 1024);
  _Float16* el = (_Float16*)(ws + (size_t)36 * 1024 * 1024);
  float*    cbs = (float*)(ws + (size_t)40 * 1024 * 1024);

  hipLaunchKernelGGL(vq_prep_z,  dim3(8192), dim3(256), 0, stream, z, zh, zl);
  hipLaunchKernelGGL(vq_prep_cb, dim3(2048), dim3(256), 0, stream, cb, eh, el, cbs);
  hipLaunchKernelGGL(vq_main,    dim3(256),  dim3(256), 0, stream,
                     zh, zl, eh, el, cbs, (int*)d_out);
}

// Round 6
// 400.888 us; speedup vs baseline: 2.2945x; 1.0905x over previous
//
#include <hip/hip_runtime.h>
#include <hip/hip_fp16.h>

// VQ codebook argmin: N=32768 queries x K=8192 codes x D=256 fp32.
// f16 hi/lo split (3 MFMA terms) => fp32-accurate dots on the matrix pipe;
// fused running argmin. Scaling (exact powers of 2, argmin-invariant):
// z*=2^4, e*=2^15; dist_scaled = 2^19*cb_sq - 2*acc.
//
// R7: OVERLAP, NOT BANDWIDTH. R6 showed traffic is irrelevant (FETCH
// 1.08GB->49MB, MfmaUtil unchanged ~47%). Correct per-SIMD MFMA cost is
// ~19.4cyc (m06 2075TF / 1024 SIMDs), so ideal = 199us; the 50% loss is
// serialization at 1 wave/SIMD (VALU 23% + latency serialize with MFMA;
// m114: overlap needs >=2 waves/SIMD). New structure:
//  - 512-thr block (8 waves = 2/SIMD), launch_bounds(512,2) (VGPR<=256)
//  - A resident in LDS (128KB), staged once, FRAG-MAJOR (prep repacks)
//    -> lane-linear ds_read_b128, no swizzle, 0 bank conflicts
//  - B loaded global->registers frag-major (prep repacks) -> coalesced
//    1KB/load, no B LDS, no dbuf, ZERO main-loop barriers: waves
//    free-run on independent (ct-stream x quadrant) work => cross-wave
//    MFMA/VALU/latency overlap
//  - reduce arrays overlay dead A region at the end

#define N_Q   32768
#define K_CB  8192
#define D_DIM 256

typedef _Float16 half8 __attribute__((ext_vector_type(8)));
typedef float    f32x4 __attribute__((ext_vector_type(4)));

__device__ __forceinline__ void gl_lds16(const _Float16* g, _Float16* l) {
  __builtin_amdgcn_global_load_lds(
      (const __attribute__((address_space(1))) unsigned int*)g,
      (__attribute__((address_space(3))) unsigned int*)l, 16, 0, 0);
}

// Frag-major layouts (half8 index):
//   zpk: ((qb*64 + q16*8 + kk)*2 + hl)*64 + l
//        = z[qb*128 + q16*16 + (l&15)][kk*32 + (l>>4)*8 + j]  (*2^4, hi/lo)
//   epk: ((c16*8  + kk)*2 + hl)*64 + l
//        = e[c16*16 + (l&15)][kk*32 + (l>>4)*8 + j]           (*2^15, hi/lo)
// Matches mfma_f32_16x16x32_f16 A/B layout: row/col = lane&15,
// k = (lane>>4)*8 + j (verified by R1/R6 passing with absmax 0).

__global__ void vq_prep_z(const float* __restrict__ z, _Float16* __restrict__ zpk) {
  int t = blockIdx.x * 256 + threadIdx.x;    // 1,048,576 threads
  int l = t & 63, g = t >> 6;                // g = qb*64 + q16*8 + kk
  int qb = g >> 6, q16 = (g >> 3) & 7, kk = g & 7;
  int row = qb * 128 + q16 * 16 + (l & 15);
  int kc  = kk * 32 + (l >> 4) * 8;
  const float4* zp = (const float4*)(z + (size_t)row * 256 + kc);
  float4 a = zp[0], b = zp[1];
  float xs[8] = {a.x, a.y, a.z, a.w, b.x, b.y, b.z, b.w};
  half8 hh, ll;
#pragma unroll
  for (int j = 0; j < 8; ++j) {
    float x = xs[j] * 16.0f;
    _Float16 hj = (_Float16)x;
    hh[j] = hj; ll[j] = (_Float16)(x - (float)hj);
  }
  ((half8*)zpk)[(size_t)g * 128 + l]      = hh;
  ((half8*)zpk)[(size_t)g * 128 + 64 + l] = ll;
}

__global__ void vq_prep_e(const float* __restrict__ cb, _Float16* __restrict__ epk) {
  int t = blockIdx.x * 256 + threadIdx.x;    // 262,144 threads
  int l = t & 63, g = t >> 6;                // g = c16*8 + kk
  int c16 = g >> 3, kk = g & 7;
  int code = c16 * 16 + (l & 15);
  int kc   = kk * 32 + (l >> 4) * 8;
  const float4* ep = (const float4*)(cb + (size_t)code * 256 + kc);
  float4 a = ep[0], b = ep[1];
  float xs[8] = {a.x, a.y, a.z, a.w, b.x, b.y, b.z, b.w};
  half8 hh, ll;
#pragma unroll
  for (int j = 0; j < 8; ++j) {
    float x = xs[j] * 32768.0f;
    _Float16 hj = (_Float16)x;
    hh[j] = hj; ll[j] = (_Float16)(x - (float)hj);
  }
  ((half8*)epk)[(size_t)g * 128 + l]      = hh;
  ((half8*)epk)[(size_t)g * 128 + 64 + l] = ll;
}

// cbs[code] = 2^19 * ||e_code||^2  (unscaled sum, like reference)
__global__ void vq_prep_cbs(const float* __restrict__ cb, float* __restrict__ cbs) {
  int w = threadIdx.x >> 6, lane = threadIdx.x & 63;
  int code = blockIdx.x * 4 + w;             // wave per code
  float4 v = ((const float4*)cb)[code * 64 + lane];
  float ss = v.x * v.x + v.y * v.y + v.z * v.z + v.w * v.w;
#pragma unroll
  for (int off = 1; off < 64; off <<= 1) ss += __shfl_xor(ss, off);
  if (lane == 0) cbs[code] = ss * 524288.0f;
}

// ---------------- main: fused GEMM + running argmin ----------------
// Grid 256 blocks (1/CU: LDS 128KB). Block = 512 thr = 8 waves = 2/SIMD.
// Wave (h,v,p): rows h*64..+64 of the block's 128 queries, cols v*64..+64
// of ct = p*32+i for i in 0..32. No barriers in the main loop.
__global__ __launch_bounds__(512, 2)
void vq_main(const _Float16* __restrict__ zpk, const _Float16* __restrict__ epk,
             const float* __restrict__ cbs, int* __restrict__ out) {
  __shared__ __align__(16) char smem[131072];   // A panel, frag-major
  _Float16* const A = (_Float16*)smem;

  const int tid  = threadIdx.x;
  const int lane = tid & 63;
  const int w    = tid >> 6;       // 0..7
  const int h    = w >> 2;         // query-row half
  const int v    = w & 1;          // code-col half
  const int p    = (w >> 1) & 1;   // ct stream (0: cts 0..31, 1: 32..63)
  const int q    = lane & 15;
  const int quad = lane >> 4;
  const int qb   = blockIdx.x;
  const int q0   = qb * 128;

  // Prologue: linear 128KB copy of this block's frag-major A panel.
  {
    const _Float16* src = zpk + (size_t)qb * 65536;
    for (int c = 0; c < 16; ++c) {
      const int off = (c * 512 + tid) * 8;     // f16 elems (16B/thread)
      gl_lds16(src + off, A + off);
    }
  }
  __syncthreads();   // drains vmcnt; A read-only from here on

  // A frags (LDS, half8 units): Ab[mt*1024 + kk*128 (+64 for lo)]
  const half8* const Ab = (const half8*)A + h * 4096 + lane;
  // B frags (global, half8 units): ebi[nt*1024 + kk*128 (+64 for lo)]
  const half8* const eb = (const half8*)epk + (size_t)p * 262144
                        + (size_t)v * 4096 + lane;

  float    rd[16];
  unsigned rc[16];
#pragma unroll
  for (int i = 0; i < 16; ++i) { rd[i] = 3.0e38f; rc[i] = 0u; }

  for (int i = 0; i < 32; ++i) {
    const int ct   = p * 32 + i;
    const int col0 = ct * 128 + v * 64 + q;
    const half8* const ebi = eb + (size_t)i * 8192;

    float cbsv[4];
#pragma unroll
    for (int nt = 0; nt < 4; ++nt) cbsv[nt] = cbs[col0 + nt * 16];

    f32x4 acc[4][4];
#pragma unroll
    for (int mt = 0; mt < 4; ++mt)
#pragma unroll
      for (int nt = 0; nt < 4; ++nt)
        acc[mt][nt] = (f32x4){0.f, 0.f, 0.f, 0.f};

#pragma unroll 2
    for (int kk = 0; kk < 8; ++kk) {
      half8 bh[4], bl[4], ah[4], al[4];
#pragma unroll
      for (int nt = 0; nt < 4; ++nt) {
        bh[nt] = ebi[nt * 1024 + kk * 128];
        bl[nt] = ebi[nt * 1024 + kk * 128 + 64];
      }
#pragma unroll
      for (int mt = 0; mt < 4; ++mt) {
        ah[mt] = Ab[mt * 1024 + kk * 128];
        al[mt] = Ab[mt * 1024 + kk * 128 + 64];
      }
#pragma unroll
      for (int mt = 0; mt < 4; ++mt)
#pragma unroll
        for (int nt = 0; nt < 4; ++nt) {
          acc[mt][nt] = __builtin_amdgcn_mfma_f32_16x16x32_f16(ah[mt], bh[nt], acc[mt][nt], 0, 0, 0);
          acc[mt][nt] = __builtin_amdgcn_mfma_f32_16x16x32_f16(ah[mt], bl[nt], acc[mt][nt], 0, 0, 0);
          acc[mt][nt] = __builtin_amdgcn_mfma_f32_16x16x32_f16(al[mt], bh[nt], acc[mt][nt], 0, 0, 0);
        }
    }

    // dist = 2^19*cb_sq - 2*acc; running (min,idx). Ascending nt / i =>
    // strict < keeps the lowest index on ties.
#pragma unroll
    for (int mt = 0; mt < 4; ++mt)
#pragma unroll
      for (int r = 0; r < 4; ++r) {
        float d = fmaf(-2.0f, acc[mt][0][r], cbsv[0]);
        unsigned cidx = (unsigned)col0;
#pragma unroll
        for (int nt = 1; nt < 4; ++nt) {
          float dn = fmaf(-2.0f, acc[mt][nt][r], cbsv[nt]);
          if (dn < d) { d = dn; cidx = (unsigned)(col0 + nt * 16); }
        }
        int ri = mt * 4 + r;
        if (d < rd[ri]) { rd[ri] = d; rc[ri] = cidx; }
      }
  }

  // Reduce: 16-lane groups hold 16 cols of the same rows; then combine the
  // 4 (v,p) candidates per row via LDS (overlaying dead A region).
  __syncthreads();                       // all waves done reading A
  float*    const redD = (float*)smem;   // [4][128]
  unsigned* const redC = (unsigned*)(smem + 2048);

#pragma unroll
  for (int ri = 0; ri < 16; ++ri) {
    float d = rd[ri]; unsigned cidx = rc[ri];
#pragma unroll
    for (int off = 1; off < 16; off <<= 1) {
      float od = __shfl_xor(d, off);
      unsigned oc = __shfl_xor(cidx, off);
      if (od < d || (od == d && oc < cidx)) { d = od; cidx = oc; }
    }
    if (q == 0) {
      int row = h * 64 + (ri >> 2) * 16 + quad * 4 + (ri & 3);
      redD[(w & 3) * 128 + row] = d;
      redC[(w & 3) * 128 + row] = cidx;
    }
  }
  __syncthreads();
  if (tid < 128) {
    float d0 = redD[tid]; unsigned c0 = redC[tid];
#pragma unroll
    for (int s = 1; s < 4; ++s) {
      float ds = redD[s * 128 + tid]; unsigned cs = redC[s * 128 + tid];
      if (ds < d0 || (ds == d0 && cs < c0)) { d0 = ds; c0 = cs; }
    }
    out[q0 + tid] = (int)c0;
  }
}

extern "C" void kernel_launch(void* const* d_in, const int* in_sizes, int n_in,
                              void* d_out, int out_size, void* d_ws, size_t ws_size,
                              hipStream_t stream) {
  const float* z  = (const float*)d_in[0];   // [32,32,32,256] fp32
  const float* cb = (const float*)d_in[1];   // [8192,256] fp32
  char* ws = (char*)d_ws;
  // ws layout (~40 MB): zpk 32M (frag-major z hi/lo) | epk 8M | cbs 32K
  _Float16* zpk = (_Float16*)(ws);
  _Float16* epk = (_Float16*)(ws + (size_t)32 * 1024 * 1024);
  float*    cbs = (float*)(ws + (size_t)40 * 1024 * 1024);

  hipLaunchKernelGGL(vq_prep_z,   dim3(4096), dim3(256), 0, stream, z, zpk);
  hipLaunchKernelGGL(vq_prep_e,   dim3(1024), dim3(256), 0, stream, cb, epk);
  hipLaunchKernelGGL(vq_prep_cbs, dim3(2048), dim3(256), 0, stream, cb, cbs);
  hipLaunchKernelGGL(vq_main,     dim3(256),  dim3(512), 0, stream,
                     zpk, epk, cbs, (int*)d_out);
}